// Round 1
// baseline (331.993 us; speedup 1.0000x reference)
//
#include <hip/hip_runtime.h>

typedef unsigned short u16;
typedef __bf16 bf16x8 __attribute__((ext_vector_type(8)));
typedef float f32x4 __attribute__((ext_vector_type(4)));
typedef unsigned short u16x4 __attribute__((ext_vector_type(4)));

static __device__ __forceinline__ u16 f2bf(float f){
  __bf16 h = (__bf16)f;
  return __builtin_bit_cast(u16, h);
}

#define MFMA(a,b,c) __builtin_amdgcn_mfma_f32_16x16x32_bf16(a,b,c,0,0,0)

// ---------------- LayerNorm: one 1024-col row per 256-thread block ----------------
__global__ __launch_bounds__(256) void ln_rows(const float* __restrict__ x,
    const float* __restrict__ g, const float* __restrict__ bta, u16* __restrict__ y)
{
  const int row = blockIdx.x;
  const int t = threadIdx.x;
  const float4 xv = ((const float4*)(x + (size_t)row*1024))[t];
  float s  = xv.x+xv.y+xv.z+xv.w;
  float sq = xv.x*xv.x+xv.y*xv.y+xv.z*xv.z+xv.w*xv.w;
  #pragma unroll
  for (int off=32; off; off>>=1){ s += __shfl_xor(s,off); sq += __shfl_xor(sq,off); }
  __shared__ float red[8];
  const int wid = t>>6, lane = t&63;
  if (lane==0){ red[wid]=s; red[4+wid]=sq; }
  __syncthreads();
  s  = red[0]+red[1]+red[2]+red[3];
  sq = red[4]+red[5]+red[6]+red[7];
  const float mu = s*(1.0f/1024.0f);
  float var = sq*(1.0f/1024.0f) - mu*mu;
  var = fmaxf(var, 0.0f);
  const float rs = rsqrtf(var + 1e-5f);
  const float4 gv = ((const float4*)g)[t];
  const float4 bv = ((const float4*)bta)[t];
  u16x4 o;
  o[0] = f2bf((xv.x-mu)*rs*gv.x + bv.x);
  o[1] = f2bf((xv.y-mu)*rs*gv.y + bv.y);
  o[2] = f2bf((xv.z-mu)*rs*gv.z + bv.z);
  o[3] = f2bf((xv.w-mu)*rs*gv.w + bv.w);
  ((u16x4*)(y + (size_t)row*1024))[t] = o;
}

// ---------------- 32x32 tiled transpose: f32 in -> bf16 out (for weights) ----------------
__global__ __launch_bounds__(256) void transpose_w(const float* __restrict__ W, u16* __restrict__ WT)
{
  __shared__ float tile[32][33];
  const int tid = threadIdx.x;
  const int r0 = blockIdx.y*32, c0 = blockIdx.x*32;
  #pragma unroll
  for (int i=0;i<4;++i){
    int idx = i*256+tid; int r = idx>>5, c = idx&31;
    tile[r][c] = W[(size_t)(r0+r)*1024 + c0+c];
  }
  __syncthreads();
  #pragma unroll
  for (int i=0;i<4;++i){
    int idx = i*256+tid; int r = idx>>5, c = idx&31;
    WT[(size_t)(c0+r)*1024 + r0+c] = f2bf(tile[c][r]);
  }
}

// ---------------- 32x32 tiled transpose: bf16 -> bf16 per batch (v -> v^T) ----------------
__global__ __launch_bounds__(256) void transpose_v(const u16* __restrict__ V, u16* __restrict__ VT)
{
  __shared__ u16 tile[32][33];
  const int tid = threadIdx.x;
  const size_t base = (size_t)blockIdx.z * 1048576;
  const int r0 = blockIdx.y*32, c0 = blockIdx.x*32;
  #pragma unroll
  for (int i=0;i<4;++i){
    int idx = i*256+tid; int r = idx>>5, c = idx&31;
    tile[r][c] = V[base + (size_t)(r0+r)*1024 + c0+c];
  }
  __syncthreads();
  #pragma unroll
  for (int i=0;i<4;++i){
    int idx = i*256+tid; int r = idx>>5, c = idx&31;
    VT[base + (size_t)(c0+r)*1024 + r0+c] = tile[c][r];
  }
}

// ---------------- GEMM: C[4096x1024] = A[4096x1024] @ Bt^T, A,Bt bf16 row-major ----------------
// Bt is [N][K] (i.e. B transposed). outf=0: bf16 out. outf=1: f32 out + bias.
__global__ __launch_bounds__(256) void gemm_bt(const u16* __restrict__ A,
    const u16* __restrict__ Bt, u16* __restrict__ Cb, float* __restrict__ Cf,
    const float* __restrict__ bias, int outf)
{
  __shared__ u16 As[128][72];   // +8 pad: 2-way-max bank aliasing on ds_read_b128
  __shared__ u16 Bs[128][72];
  const int tid = threadIdx.x, lane = tid&63, wid = tid>>6;
  const int l15 = lane&15, l4 = lane>>4;
  const int m0 = blockIdx.y*128, n0 = blockIdx.x*128;
  const int wr = wid>>1, wc = wid&1;        // 2x2 wave grid, 64x64 per wave
  const int srow = tid>>3, scol = (tid&7)*8;
  const u16* Ag = A  + (size_t)(m0+srow)*1024 + scol;
  const u16* Bg = Bt + (size_t)(n0+srow)*1024 + scol;
  f32x4 acc[4][4];
  #pragma unroll
  for (int mt=0;mt<4;++mt)
    #pragma unroll
    for (int nt=0;nt<4;++nt) acc[mt][nt] = f32x4{0,0,0,0};

  for (int kt=0; kt<16; ++kt){
    const int k0 = kt*64;
    #pragma unroll
    for (int it=0; it<4; ++it){
      *(bf16x8*)&As[srow+it*32][scol] = *(const bf16x8*)(Ag + (size_t)it*32*1024 + k0);
      *(bf16x8*)&Bs[srow+it*32][scol] = *(const bf16x8*)(Bg + (size_t)it*32*1024 + k0);
    }
    __syncthreads();
    #pragma unroll
    for (int kk=0; kk<2; ++kk){
      bf16x8 af[4], bfv[4];
      #pragma unroll
      for (int mt=0;mt<4;++mt) af[mt]  = *(const bf16x8*)&As[wr*64+mt*16+l15][kk*32+8*l4];
      #pragma unroll
      for (int nt=0;nt<4;++nt) bfv[nt] = *(const bf16x8*)&Bs[wc*64+nt*16+l15][kk*32+8*l4];
      #pragma unroll
      for (int mt=0;mt<4;++mt)
        #pragma unroll
        for (int nt=0;nt<4;++nt)
          acc[mt][nt] = MFMA(af[mt], bfv[nt], acc[mt][nt]);
    }
    __syncthreads();
  }
  #pragma unroll
  for (int mt=0;mt<4;++mt)
    #pragma unroll
    for (int nt=0;nt<4;++nt)
      #pragma unroll
      for (int r=0;r<4;++r){
        const int row = m0 + wr*64+mt*16+l4*4+r;
        const int col = n0 + wc*64+nt*16+l15;
        if (outf) Cf[(size_t)row*1024+col] = acc[mt][nt][r] + bias[col];
        else      Cb[(size_t)row*1024+col] = f2bf(acc[mt][nt][r]);
      }
}

// ---------------- softmax stats: m,l per (b,g,i) via MFMA QK^T ----------------
__global__ __launch_bounds__(256) void attn_stats(const u16* __restrict__ qk,
    const u16* __restrict__ v, float* __restrict__ m_arr, float* __restrict__ l_arr)
{
  const int lane = threadIdx.x & 63, wid = threadIdx.x >> 6;
  const int l15 = lane&15, l4 = lane>>4;
  const int b = blockIdx.z, g = blockIdx.y;
  const int i_base = blockIdx.x*64 + wid*16;
  const u16* qrow = qk + (size_t)(b*1024 + i_base + l15)*1024 + g*64 + 8*l4;
  const bf16x8 a0 = *(const bf16x8*)(qrow);
  const bf16x8 a1 = *(const bf16x8*)(qrow + 32);
  float mx[4] = {-1e30f,-1e30f,-1e30f,-1e30f};
  float sm[4] = {0.f,0.f,0.f,0.f};
  const u16* vbase = v + (size_t)(b*1024 + l15)*1024 + g*64 + 8*l4;
  for (int jt=0; jt<64; ++jt){
    const u16* vrow = vbase + (size_t)jt*16*1024;
    f32x4 c = {0,0,0,0};
    c = MFMA(a0, *(const bf16x8*)(vrow),      c);
    c = MFMA(a1, *(const bf16x8*)(vrow + 32), c);
    #pragma unroll
    for (int r=0;r<4;++r){
      const float s = c[r]*0.125f;
      const float nm = fmaxf(mx[r], s);
      sm[r] = sm[r]*__expf(mx[r]-nm) + __expf(s-nm);
      mx[r] = nm;
    }
  }
  #pragma unroll
  for (int r=0;r<4;++r){
    #pragma unroll
    for (int msk=1; msk<16; msk<<=1){
      const float om = __shfl_xor(mx[r], msk);
      const float os = __shfl_xor(sm[r], msk);
      const float nm = fmaxf(mx[r], om);
      sm[r] = sm[r]*__expf(mx[r]-nm) + os*__expf(om-nm);
      mx[r] = nm;
    }
  }
  if (l15 == 0){
    #pragma unroll
    for (int r=0;r<4;++r){
      const int i = i_base + l4*4 + r;
      const size_t idx = (size_t)(b*16+g)*1024 + i;
      m_arr[idx] = mx[r];
      l_arr[idx] = sm[r];
    }
  }
}

// ---------------- fused: recompute sim, softmax, talking-heads mix, PV ----------------
__global__ __launch_bounds__(256) void attn_mix_pv(const u16* __restrict__ qk,
    const u16* __restrict__ v, const u16* __restrict__ vt,
    const float* __restrict__ m_arr, const float* __restrict__ l_arr,
    const float* __restrict__ Wth, u16* __restrict__ attn_out)
{
  __shared__ float wth[256];
  __shared__ float P[16][16][36];   // [g][i][j(+pad)] : pad 36 -> 2-way-max aliasing
  const int tid = threadIdx.x;
  const int lane = tid&63, wid = tid>>6;
  const int l15 = lane&15, l4 = lane>>4;
  const int b = blockIdx.y;
  const int i0 = blockIdx.x*16;
  wth[tid] = Wth[tid];
  // stats for this wave's 4 heads g, this lane's 4 sim rows
  float mxs[4][4], ils[4][4];
  #pragma unroll
  for (int gg=0; gg<4; ++gg){
    const int g = wid*4+gg;
    #pragma unroll
    for (int r=0;r<4;++r){
      const size_t idx = (size_t)(b*16+g)*1024 + i0 + l4*4 + r;
      mxs[gg][r] = m_arr[idx];
      ils[gg][r] = 1.0f / l_arr[idx];
    }
  }
  // qk A-fragments (reused across the whole j loop)
  bf16x8 aq[4][2];
  #pragma unroll
  for (int gg=0; gg<4; ++gg){
    const u16* qrow = qk + (size_t)(b*1024 + i0 + l15)*1024 + (wid*4+gg)*64 + 8*l4;
    aq[gg][0] = *(const bf16x8*)(qrow);
    aq[gg][1] = *(const bf16x8*)(qrow + 32);
  }
  f32x4 accO[4][4];
  #pragma unroll
  for (int hh=0;hh<4;++hh)
    #pragma unroll
    for (int dt=0;dt<4;++dt) accO[hh][dt] = f32x4{0,0,0,0};
  __syncthreads();

  for (int jt=0; jt<32; ++jt){
    const int j0 = jt*32;
    // sim for this wave's 4 g, 16i x 32j
    #pragma unroll
    for (int gg=0; gg<4; ++gg){
      const int g = wid*4+gg;
      #pragma unroll
      for (int jh=0; jh<2; ++jh){
        const u16* vrow = v + (size_t)(b*1024 + j0 + jh*16 + l15)*1024 + g*64 + 8*l4;
        f32x4 c = {0,0,0,0};
        c = MFMA(aq[gg][0], *(const bf16x8*)(vrow),      c);
        c = MFMA(aq[gg][1], *(const bf16x8*)(vrow + 32), c);
        #pragma unroll
        for (int r=0;r<4;++r){
          const float p = __expf(c[r]*0.125f - mxs[gg][r]) * ils[gg][r];
          P[g][l4*4+r][jh*16+l15] = p;
        }
      }
    }
    __syncthreads();
    // talking-heads mix at A-fragment positions: i=l15, j=8*l4..8*l4+7
    float bh[4][8];
    #pragma unroll
    for (int hh=0;hh<4;++hh)
      #pragma unroll
      for (int e=0;e<8;++e) bh[hh][e] = 0.f;
    #pragma unroll
    for (int g2=0; g2<16; ++g2){
      const f32x4 p0 = *(const f32x4*)&P[g2][l15][8*l4];
      const f32x4 p1 = *(const f32x4*)&P[g2][l15][8*l4+4];
      #pragma unroll
      for (int hh=0; hh<4; ++hh){
        const float w = wth[(wid*4+hh)*16+g2];
        #pragma unroll
        for (int e=0;e<4;++e){ bh[hh][e] += w*p0[e]; bh[hh][4+e] += w*p1[e]; }
      }
    }
    // PV: accO[h][dt] += B_h(16i x 32j) @ v^T-sourced fragment
    #pragma unroll
    for (int hh=0; hh<4; ++hh){
      bf16x8 bfrag;
      #pragma unroll
      for (int e=0;e<8;++e) bfrag[e] = (__bf16)bh[hh][e];
      #pragma unroll
      for (int dt=0; dt<4; ++dt){
        const int c = (wid*4+hh)*64 + dt*16 + l15;
        const u16* vtrow = vt + (size_t)b*1048576 + (size_t)c*1024 + j0 + 8*l4;
        accO[hh][dt] = MFMA(bfrag, *(const bf16x8*)(vtrow), accO[hh][dt]);
      }
    }
    __syncthreads();
  }
  #pragma unroll
  for (int hh=0; hh<4; ++hh)
    #pragma unroll
    for (int dt=0; dt<4; ++dt)
      #pragma unroll
      for (int r=0;r<4;++r){
        const int i = i0 + l4*4 + r;
        const int col = (wid*4+hh)*64 + dt*16 + l15;
        attn_out[(size_t)(b*1024+i)*1024 + col] = f2bf(accO[hh][dt][r]);
      }
}

extern "C" void kernel_launch(void* const* d_in, const int* in_sizes, int n_in,
                              void* d_out, int out_size, void* d_ws, size_t ws_size,
                              hipStream_t stream) {
  const float* text    = (const float*)d_in[0];
  const float* audio   = (const float*)d_in[1];
  const float* g_text  = (const float*)d_in[2];
  const float* b_text  = (const float*)d_in[3];
  const float* g_audio = (const float*)d_in[4];
  const float* b_audio = (const float*)d_in[5];
  const float* W_qk    = (const float*)d_in[6];
  const float* W_v     = (const float*)d_in[7];
  const float* W_out   = (const float*)d_in[8];
  const float* b_out   = (const float*)d_in[9];
  const float* W_th    = (const float*)d_in[10];

  char* ws = (char*)d_ws;
  const size_t MB = 1024*1024;
  u16* text_n  = (u16*)(ws + 0*MB);    // 8 MB
  u16* audio_n = (u16*)(ws + 8*MB);    // 8 MB
  u16* WqkT    = (u16*)(ws + 16*MB);   // 2 MB
  u16* WvT     = (u16*)(ws + 18*MB);   // 2 MB
  u16* WoutT   = (u16*)(ws + 20*MB);   // 2 MB
  u16* qk      = (u16*)(ws + 22*MB);   // 8 MB
  u16* v       = (u16*)(ws + 30*MB);   // 8 MB
  u16* vt      = (u16*)(ws + 38*MB);   // 8 MB
  float* m_arr = (float*)(ws + 46*MB); // 256 KB
  float* l_arr = (float*)(ws + 47*MB); // 256 KB
  u16* attn_o  = (u16*)(ws + 48*MB);   // 8 MB

  transpose_w<<<dim3(32,32), 256, 0, stream>>>(W_qk,  WqkT);
  transpose_w<<<dim3(32,32), 256, 0, stream>>>(W_v,   WvT);
  transpose_w<<<dim3(32,32), 256, 0, stream>>>(W_out, WoutT);
  ln_rows<<<4096, 256, 0, stream>>>(text,  g_text,  b_text,  text_n);
  ln_rows<<<4096, 256, 0, stream>>>(audio, g_audio, b_audio, audio_n);
  gemm_bt<<<dim3(8,32), 256, 0, stream>>>(audio_n, WqkT, qk, nullptr, nullptr, 0);
  gemm_bt<<<dim3(8,32), 256, 0, stream>>>(text_n,  WvT,  v,  nullptr, nullptr, 0);
  transpose_v<<<dim3(32,32,4), 256, 0, stream>>>(v, vt);
  attn_stats<<<dim3(16,16,4), 256, 0, stream>>>(qk, v, m_arr, l_arr);
  attn_mix_pv<<<dim3(64,4), 256, 0, stream>>>(qk, v, vt, m_arr, l_arr, W_th, attn_o);
  gemm_bt<<<dim3(8,32), 256, 0, stream>>>(attn_o, WoutT, nullptr, (float*)d_out, b_out, 1);
}

// Round 4
// 314.465 us; speedup vs baseline: 1.0557x; 1.0557x over previous
//
#include <hip/hip_runtime.h>

typedef unsigned short u16;
typedef __bf16 bf16x8 __attribute__((ext_vector_type(8)));
typedef float f32x4 __attribute__((ext_vector_type(4)));
typedef unsigned short u16x4 __attribute__((ext_vector_type(4)));

static __device__ __forceinline__ u16 f2bf(float f){
  __bf16 h = (__bf16)f;
  return __builtin_bit_cast(u16, h);
}

#define MFMA(a,b,c) __builtin_amdgcn_mfma_f32_16x16x32_bf16(a,b,c,0,0,0)

// ---------------- LayerNorm: one 1024-col row per 256-thread block ----------------
__global__ __launch_bounds__(256) void ln_rows(const float* __restrict__ x,
    const float* __restrict__ g, const float* __restrict__ bta, u16* __restrict__ y)
{
  const int row = blockIdx.x;
  const int t = threadIdx.x;
  const float4 xv = ((const float4*)(x + (size_t)row*1024))[t];
  float s  = xv.x+xv.y+xv.z+xv.w;
  float sq = xv.x*xv.x+xv.y*xv.y+xv.z*xv.z+xv.w*xv.w;
  #pragma unroll
  for (int off=32; off; off>>=1){ s += __shfl_xor(s,off); sq += __shfl_xor(sq,off); }
  __shared__ float red[8];
  const int wid = t>>6, lane = t&63;
  if (lane==0){ red[wid]=s; red[4+wid]=sq; }
  __syncthreads();
  s  = red[0]+red[1]+red[2]+red[3];
  sq = red[4]+red[5]+red[6]+red[7];
  const float mu = s*(1.0f/1024.0f);
  float var = sq*(1.0f/1024.0f) - mu*mu;
  var = fmaxf(var, 0.0f);
  const float rs = rsqrtf(var + 1e-5f);
  const float4 gv = ((const float4*)g)[t];
  const float4 bv = ((const float4*)bta)[t];
  u16x4 o;
  o[0] = f2bf((xv.x-mu)*rs*gv.x + bv.x);
  o[1] = f2bf((xv.y-mu)*rs*gv.y + bv.y);
  o[2] = f2bf((xv.z-mu)*rs*gv.z + bv.z);
  o[3] = f2bf((xv.w-mu)*rs*gv.w + bv.w);
  ((u16x4*)(y + (size_t)row*1024))[t] = o;
}

// ---------------- 32x32 tiled transpose: f32 in -> bf16 out (for weights) ----------------
__global__ __launch_bounds__(256) void transpose_w(const float* __restrict__ W, u16* __restrict__ WT)
{
  __shared__ float tile[32][33];
  const int tid = threadIdx.x;
  const int r0 = blockIdx.y*32, c0 = blockIdx.x*32;
  #pragma unroll
  for (int i=0;i<4;++i){
    int idx = i*256+tid; int r = idx>>5, c = idx&31;
    tile[r][c] = W[(size_t)(r0+r)*1024 + c0+c];
  }
  __syncthreads();
  #pragma unroll
  for (int i=0;i<4;++i){
    int idx = i*256+tid; int r = idx>>5, c = idx&31;
    WT[(size_t)(c0+r)*1024 + r0+c] = f2bf(tile[c][r]);
  }
}

// ---------------- 32x32 tiled transpose: bf16 -> bf16 per batch (v -> v^T) ----------------
__global__ __launch_bounds__(256) void transpose_v(const u16* __restrict__ V, u16* __restrict__ VT)
{
  __shared__ u16 tile[32][33];
  const int tid = threadIdx.x;
  const size_t base = (size_t)blockIdx.z * 1048576;
  const int r0 = blockIdx.y*32, c0 = blockIdx.x*32;
  #pragma unroll
  for (int i=0;i<4;++i){
    int idx = i*256+tid; int r = idx>>5, c = idx&31;
    tile[r][c] = V[base + (size_t)(r0+r)*1024 + c0+c];
  }
  __syncthreads();
  #pragma unroll
  for (int i=0;i<4;++i){
    int idx = i*256+tid; int r = idx>>5, c = idx&31;
    VT[base + (size_t)(c0+r)*1024 + r0+c] = tile[c][r];
  }
}

// ---------------- GEMM: C[4096x1024] = A[4096x1024] @ Bt^T, A,Bt bf16 row-major ----------------
__global__ __launch_bounds__(256) void gemm_bt(const u16* __restrict__ A,
    const u16* __restrict__ Bt, u16* __restrict__ Cb, float* __restrict__ Cf,
    const float* __restrict__ bias, int outf)
{
  __shared__ u16 As[128][72];
  __shared__ u16 Bs[128][72];
  const int tid = threadIdx.x, lane = tid&63, wid = tid>>6;
  const int l15 = lane&15, l4 = lane>>4;
  const int m0 = blockIdx.y*128, n0 = blockIdx.x*128;
  const int wr = wid>>1, wc = wid&1;
  const int srow = tid>>3, scol = (tid&7)*8;
  const u16* Ag = A  + (size_t)(m0+srow)*1024 + scol;
  const u16* Bg = Bt + (size_t)(n0+srow)*1024 + scol;
  f32x4 acc[4][4];
  #pragma unroll
  for (int mt=0;mt<4;++mt)
    #pragma unroll
    for (int nt=0;nt<4;++nt) acc[mt][nt] = f32x4{0,0,0,0};

  for (int kt=0; kt<16; ++kt){
    const int k0 = kt*64;
    #pragma unroll
    for (int it=0; it<4; ++it){
      *(bf16x8*)&As[srow+it*32][scol] = *(const bf16x8*)(Ag + (size_t)it*32*1024 + k0);
      *(bf16x8*)&Bs[srow+it*32][scol] = *(const bf16x8*)(Bg + (size_t)it*32*1024 + k0);
    }
    __syncthreads();
    #pragma unroll
    for (int kk=0; kk<2; ++kk){
      bf16x8 af[4], bfv[4];
      #pragma unroll
      for (int mt=0;mt<4;++mt) af[mt]  = *(const bf16x8*)&As[wr*64+mt*16+l15][kk*32+8*l4];
      #pragma unroll
      for (int nt=0;nt<4;++nt) bfv[nt] = *(const bf16x8*)&Bs[wc*64+nt*16+l15][kk*32+8*l4];
      #pragma unroll
      for (int mt=0;mt<4;++mt)
        #pragma unroll
        for (int nt=0;nt<4;++nt)
          acc[mt][nt] = MFMA(af[mt], bfv[nt], acc[mt][nt]);
    }
    __syncthreads();
  }
  #pragma unroll
  for (int mt=0;mt<4;++mt)
    #pragma unroll
    for (int nt=0;nt<4;++nt)
      #pragma unroll
      for (int r=0;r<4;++r){
        const int row = m0 + wr*64+mt*16+l4*4+r;
        const int col = n0 + wc*64+nt*16+l15;
        if (outf) Cf[(size_t)row*1024+col] = acc[mt][nt][r] + bias[col];
        else      Cb[(size_t)row*1024+col] = f2bf(acc[mt][nt][r]);
      }
}

// ---------------- softmax stats: m,l per (b,g,i) via MFMA QK^T (verbatim R1) ----------------
__global__ __launch_bounds__(256) void attn_stats(const u16* __restrict__ qk,
    const u16* __restrict__ v, float* __restrict__ m_arr, float* __restrict__ l_arr)
{
  const int lane = threadIdx.x & 63, wid = threadIdx.x >> 6;
  const int l15 = lane&15, l4 = lane>>4;
  const int b = blockIdx.z, g = blockIdx.y;
  const int i_base = blockIdx.x*64 + wid*16;
  const u16* qrow = qk + (size_t)(b*1024 + i_base + l15)*1024 + g*64 + 8*l4;
  const bf16x8 a0 = *(const bf16x8*)(qrow);
  const bf16x8 a1 = *(const bf16x8*)(qrow + 32);
  float mx[4] = {-1e30f,-1e30f,-1e30f,-1e30f};
  float sm[4] = {0.f,0.f,0.f,0.f};
  const u16* vbase = v + (size_t)(b*1024 + l15)*1024 + g*64 + 8*l4;
  for (int jt=0; jt<64; ++jt){
    const u16* vrow = vbase + (size_t)jt*16*1024;
    f32x4 c = {0,0,0,0};
    c = MFMA(a0, *(const bf16x8*)(vrow),      c);
    c = MFMA(a1, *(const bf16x8*)(vrow + 32), c);
    #pragma unroll
    for (int r=0;r<4;++r){
      const float s = c[r]*0.125f;
      const float nm = fmaxf(mx[r], s);
      sm[r] = sm[r]*__expf(mx[r]-nm) + __expf(s-nm);
      mx[r] = nm;
    }
  }
  #pragma unroll
  for (int r=0;r<4;++r){
    #pragma unroll
    for (int msk=1; msk<16; msk<<=1){
      const float om = __shfl_xor(mx[r], msk);
      const float os = __shfl_xor(sm[r], msk);
      const float nm = fmaxf(mx[r], om);
      sm[r] = sm[r]*__expf(mx[r]-nm) + os*__expf(om-nm);
      mx[r] = nm;
    }
  }
  if (l15 == 0){
    #pragma unroll
    for (int r=0;r<4;++r){
      const int i = i_base + l4*4 + r;
      const size_t idx = (size_t)(b*16+g)*1024 + i;
      m_arr[idx] = mx[r];
      l_arr[idx] = sm[r];
    }
  }
}

// ---------------- fused mix+PV (R1-verified math, 8 waves, j-chunked) ----------------
// Block (i-tile, b, z-chunk). Wave wid: P-phase computes heads g=2wid,2wid+1 (normalized
// via stats); mix+PV phase covers OUTPUT heads h=2wid,2wid+1 using V_h (vt). Writes a full
// f32 partial-U slice for its j-range; reduce_u sums slices. No atomics, no memset needed.
__global__ __launch_bounds__(512,4) void attn_mix_pv2(const u16* __restrict__ qk,
    const u16* __restrict__ v, const u16* __restrict__ vt,
    const float* __restrict__ m_arr, const float* __restrict__ l_arr,
    const float* __restrict__ Wth, float* __restrict__ Upart, int njt)
{
  __shared__ float wth[256];
  __shared__ float P[16][16][36];
  const int tid = threadIdx.x;
  const int lane = tid&63, wid = tid>>6;
  const int l15 = lane&15, l4 = lane>>4;
  const int b = blockIdx.y, z = blockIdx.z;
  const int i0 = blockIdx.x*16;
  const size_t bb = (size_t)b*1048576;
  if (tid < 256) wth[tid] = Wth[tid];

  // stats + qk A-fragments for this wave's 2 P-heads
  float mxs[2][4], ils[2][4];
  bf16x8 aq[2][2];
  #pragma unroll
  for (int gg=0; gg<2; ++gg){
    const int g = 2*wid+gg;
    #pragma unroll
    for (int r=0;r<4;++r){
      const size_t idx = (size_t)(b*16+g)*1024 + i0 + 4*l4 + r;
      mxs[gg][r] = m_arr[idx];
      ils[gg][r] = 1.0f / l_arr[idx];
    }
    const u16* qrow = qk + bb + (size_t)(i0+l15)*1024 + g*64 + 8*l4;
    aq[gg][0] = *(const bf16x8*)qrow;
    aq[gg][1] = *(const bf16x8*)(qrow+32);
  }
  f32x4 acc[2][4];
  #pragma unroll
  for (int hh=0;hh<2;++hh)
    #pragma unroll
    for (int dt=0;dt<4;++dt) acc[hh][dt] = f32x4{0,0,0,0};

  for (int jt=0; jt<njt; ++jt){
    const int j0 = (z*njt + jt)*32;
    // P-phase: normalized P for heads 2wid, 2wid+1 (R1 pattern)
    #pragma unroll
    for (int gg=0; gg<2; ++gg){
      const int g = 2*wid+gg;
      #pragma unroll
      for (int jh=0; jh<2; ++jh){
        const u16* vrow = v + bb + (size_t)(j0 + jh*16 + l15)*1024 + g*64 + 8*l4;
        f32x4 c = {0,0,0,0};
        c = MFMA(aq[gg][0], *(const bf16x8*)(vrow),      c);
        c = MFMA(aq[gg][1], *(const bf16x8*)(vrow + 32), c);
        #pragma unroll
        for (int r=0;r<4;++r)
          P[g][4*l4+r][jh*16+l15] = __expf(c[r]*0.125f - mxs[gg][r]) * ils[gg][r];
      }
    }
    __syncthreads();
    // mix (pre-PV, all 16 g) + PV with V_h for output heads 2wid, 2wid+1
    #pragma unroll
    for (int hh=0; hh<2; ++hh){
      const int h = 2*wid+hh;
      float bh[8];
      #pragma unroll
      for (int e=0;e<8;++e) bh[e] = 0.f;
      #pragma unroll
      for (int g2=0; g2<16; ++g2){
        const f32x4 p0 = *(const f32x4*)&P[g2][l15][8*l4];
        const f32x4 p1 = *(const f32x4*)&P[g2][l15][8*l4+4];
        const float w = wth[h*16+g2];
        #pragma unroll
        for (int e=0;e<4;++e){ bh[e] += w*p0[e]; bh[4+e] += w*p1[e]; }
      }
      bf16x8 pf;
      #pragma unroll
      for (int e=0;e<8;++e) pf[e] = (__bf16)bh[e];
      const u16* vtr = vt + bb + (size_t)(h*64 + l15)*1024 + j0 + 8*l4;
      #pragma unroll
      for (int dt=0; dt<4; ++dt)
        acc[hh][dt] = MFMA(pf, *(const bf16x8*)(vtr + (size_t)dt*16*1024), acc[hh][dt]);
    }
    __syncthreads();
  }
  #pragma unroll
  for (int hh=0; hh<2; ++hh)
    #pragma unroll
    for (int dt=0; dt<4; ++dt)
      #pragma unroll
      for (int r=0;r<4;++r){
        const size_t row = (size_t)z*4096 + b*1024 + i0 + 4*l4 + r;
        Upart[row*1024 + (2*wid+hh)*64 + dt*16 + l15] = acc[hh][dt][r];
      }
}

// ---------------- reduce partial U slices -> bf16 attn_o ----------------
__global__ __launch_bounds__(256) void reduce_u(const float* __restrict__ Upart,
    u16* __restrict__ attn_o, int jc)
{
  const int row = blockIdx.x;        // b*1024 + i
  const int t = threadIdx.x;
  f32x4 s = *(const f32x4*)(Upart + (size_t)row*1024 + 4*t);
  for (int z=1; z<jc; ++z)
    s += *(const f32x4*)(Upart + ((size_t)z*4096 + row)*1024 + 4*t);
  u16x4 o;
  #pragma unroll
  for (int e=0;e<4;++e) o[e] = f2bf(s[e]);
  *(u16x4*)(attn_o + (size_t)row*1024 + 4*t) = o;
}

extern "C" void kernel_launch(void* const* d_in, const int* in_sizes, int n_in,
                              void* d_out, int out_size, void* d_ws, size_t ws_size,
                              hipStream_t stream) {
  const float* text    = (const float*)d_in[0];
  const float* audio   = (const float*)d_in[1];
  const float* g_text  = (const float*)d_in[2];
  const float* b_text  = (const float*)d_in[3];
  const float* g_audio = (const float*)d_in[4];
  const float* b_audio = (const float*)d_in[5];
  const float* W_qk    = (const float*)d_in[6];
  const float* W_v     = (const float*)d_in[7];
  const float* W_out   = (const float*)d_in[8];
  const float* b_out   = (const float*)d_in[9];
  const float* W_th    = (const float*)d_in[10];

  char* ws = (char*)d_ws;
  const size_t MB = 1024*1024;
  u16* text_n  = (u16*)(ws + 0*MB);    // dead after gemm v
  u16* audio_n = (u16*)(ws + 8*MB);    // dead after gemm qk
  u16* WqkT    = (u16*)(ws + 16*MB);   // dead after gemm qk -> reused by m/l
  u16* WvT     = (u16*)(ws + 18*MB);
  u16* WoutT   = (u16*)(ws + 20*MB);   // live until final gemm
  u16* qk      = (u16*)(ws + 22*MB);
  u16* v       = (u16*)(ws + 30*MB);
  u16* vt      = (u16*)(ws + 38*MB);
  float* m_arr = (float*)(ws + 16*MB);           // 256 KB (WqkT dead)
  float* l_arr = (float*)(ws + 16*MB + 256*1024);

  // j-chunk count: 4 if workspace allows the 64 MB partial buffer at +46MB, else 1.
  const int jc = (ws_size >= 110*MB) ? 4 : 1;
  float* Upart;
  u16* attn_o;
  if (jc == 4){ Upart = (float*)(ws + 46*MB); attn_o = (u16*)(ws + 0*MB); }
  else        { Upart = (float*)(ws + 0*MB);  attn_o = (u16*)(ws + 46*MB); }

  transpose_w<<<dim3(32,32), 256, 0, stream>>>(W_qk,  WqkT);
  transpose_w<<<dim3(32,32), 256, 0, stream>>>(W_v,   WvT);
  transpose_w<<<dim3(32,32), 256, 0, stream>>>(W_out, WoutT);
  ln_rows<<<4096, 256, 0, stream>>>(text,  g_text,  b_text,  text_n);
  ln_rows<<<4096, 256, 0, stream>>>(audio, g_audio, b_audio, audio_n);
  gemm_bt<<<dim3(8,32), 256, 0, stream>>>(audio_n, WqkT, qk, nullptr, nullptr, 0);
  gemm_bt<<<dim3(8,32), 256, 0, stream>>>(text_n,  WvT,  v,  nullptr, nullptr, 0);
  transpose_v<<<dim3(32,32,4), 256, 0, stream>>>(v, vt);
  attn_stats<<<dim3(16,16,4), 256, 0, stream>>>(qk, v, m_arr, l_arr);
  attn_mix_pv2<<<dim3(64,4,jc), 512, 0, stream>>>(qk, v, vt, m_arr, l_arr, W_th, Upart, 32/jc);
  reduce_u<<<4096, 256, 0, stream>>>(Upart, attn_o, jc);
  gemm_bt<<<dim3(8,32), 256, 0, stream>>>(attn_o, WoutT, nullptr, (float*)d_out, b_out, 1);
}